// Round 1
// baseline (433.743 us; speedup 1.0000x reference)
//
#include <hip/hip_runtime.h>

// DWT1DForward db4 periodic J=3, fused single kernel.
// x: (16,64,65536) fp32 -> out concat [lo3(1024*8192), hi1(1024*32768),
//                                      hi2(1024*16384), hi3(1024*8192)]
//
// Key identity: one analysis level == out[i] = sum_t h[t]*x[(2i+t-3) mod N].
// (roll(-4) + pad(7) + VALID stride-2 conv + wrap-add == periodic conv, offset -3)

#define N0      65536
#define CHUNK_S 8192
#define NROWS   1024
#define BD      512

// output element offsets (fp32 elements)
#define OFF_LO3 0ul
#define OFF_HI1 8388608ul    // 1024*8192
#define OFF_HI2 41943040ul   // + 1024*32768
#define OFF_HI3 58720256ul   // + 1024*16384

__global__ __launch_bounds__(BD, 4)
void dwt3_fused(const float* __restrict__ x,
                const float* __restrict__ h0,
                const float* __restrict__ h1,
                float* __restrict__ out) {
    // sx  : x[base-23 .. base+8214]          phys p = n - base + 23   (8238)
    // slo1: lo1[base1-10 .. base1+4105]      phys p = k - base1 + 11  (4117, +1 shift for even windows)
    // slo2: lo2[base2-3 .. base2+2050]       phys p = j - base2 + 3   (2054)
    __shared__ __align__(16) float sx[8238];
    __shared__ __align__(16) float slo1[4117];
    __shared__ __align__(16) float slo2[2054];

    const int tid   = threadIdx.x;
    const int bid   = blockIdx.x;
    const int row   = bid >> 3;
    const int chunk = bid & 7;
    const int base  = chunk * CHUNK_S;
    const size_t rowOff = (size_t)row * N0;

    float h0f[8], h1f[8];
#pragma unroll
    for (int t = 0; t < 8; ++t) { h0f[t] = h0[t]; h1f[t] = h1[t]; }

    // ---- stage x chunk + periodic halo into LDS ----
    const float4* x4 = reinterpret_cast<const float4*>(x + rowOff + base);
#pragma unroll
    for (int m = tid; m < CHUNK_S / 4; m += BD) {   // exactly 4 iters/thread
        float4 v = x4[m];
        int p = 23 + 4 * m;
        sx[p]   = v.x; sx[p+1] = v.y; sx[p+2] = v.z; sx[p+3] = v.w;
    }
    for (int i = tid; i < 46; i += BD) {            // halo: 23 left, 23 right
        int g, p;
        if (i < 23) { g = base - 23 + i;           p = i; }
        else        { g = base + CHUNK_S + (i-23); p = CHUNK_S + i; }
        if (g < 0)    g += N0;
        if (g >= N0)  g -= N0;
        sx[p] = x[rowOff + g];
    }
    __syncthreads();

    // ---- level 1: x -> lo1 (LDS, halo +-10), hi1 -> global ----
    // lo1[k], k = base1-10+kk : window sx phys [2kk .. 2kk+7] (even start)
    const float2* sx2 = reinterpret_cast<const float2*>(sx);
    float* hi1 = out + OFF_HI1 + (size_t)row * 32768 + (size_t)chunk * 4096;
    for (int kk = tid; kk < 4116; kk += BD) {
        float2 p0 = sx2[kk], p1 = sx2[kk+1], p2 = sx2[kk+2], p3 = sx2[kk+3];
        float v[8] = {p0.x, p0.y, p1.x, p1.y, p2.x, p2.y, p3.x, p3.y};
        float s0 = 0.f, s1 = 0.f;
#pragma unroll
        for (int t = 0; t < 8; ++t) {
            s0 = fmaf(h0f[t], v[t], s0);
            s1 = fmaf(h1f[t], v[t], s1);
        }
        slo1[kk + 1] = s0;                       // +1 shift: level-2 windows even
        unsigned k = (unsigned)(kk - 10);
        if (k < 4096u) hi1[k] = s1;
    }
    __syncthreads();

    // ---- level 2: lo1 -> lo2 (LDS, halo +-3), hi2 -> global ----
    // lo2[j], j = base2-3+jj : window slo1 phys [2jj+2 .. 2jj+9] (even start)
    const float2* slo1_2 = reinterpret_cast<const float2*>(slo1);
    float* hi2 = out + OFF_HI2 + (size_t)row * 16384 + (size_t)chunk * 2048;
    for (int jj = tid; jj < 2054; jj += BD) {
        float2 q0 = slo1_2[jj+1], q1 = slo1_2[jj+2], q2 = slo1_2[jj+3], q3 = slo1_2[jj+4];
        float v[8] = {q0.x, q0.y, q1.x, q1.y, q2.x, q2.y, q3.x, q3.y};
        float s0 = 0.f, s1 = 0.f;
#pragma unroll
        for (int t = 0; t < 8; ++t) {
            s0 = fmaf(h0f[t], v[t], s0);
            s1 = fmaf(h1f[t], v[t], s1);
        }
        slo2[jj] = s0;
        unsigned j = (unsigned)(jj - 3);
        if (j < 2048u) hi2[j] = s1;
    }
    __syncthreads();

    // ---- level 3: lo2 -> lo3, hi3 -> global ----
    // lo3[i], i = base3+ii : window slo2 phys [2ii .. 2ii+7] (even start)
    const float2* slo2_2 = reinterpret_cast<const float2*>(slo2);
    float* lo3 = out + OFF_LO3 + (size_t)row * 8192 + (size_t)chunk * 1024;
    float* hi3 = out + OFF_HI3 + (size_t)row * 8192 + (size_t)chunk * 1024;
    for (int ii = tid; ii < 1024; ii += BD) {    // exactly 2 iters/thread
        float2 r0 = slo2_2[ii], r1 = slo2_2[ii+1], r2 = slo2_2[ii+2], r3 = slo2_2[ii+3];
        float v[8] = {r0.x, r0.y, r1.x, r1.y, r2.x, r2.y, r3.x, r3.y};
        float s0 = 0.f, s1 = 0.f;
#pragma unroll
        for (int t = 0; t < 8; ++t) {
            s0 = fmaf(h0f[t], v[t], s0);
            s1 = fmaf(h1f[t], v[t], s1);
        }
        lo3[ii] = s0;
        hi3[ii] = s1;
    }
}

extern "C" void kernel_launch(void* const* d_in, const int* in_sizes, int n_in,
                              void* d_out, int out_size, void* d_ws, size_t ws_size,
                              hipStream_t stream) {
    const float* x  = (const float*)d_in[0];
    const float* h0 = (const float*)d_in[1];
    const float* h1 = (const float*)d_in[2];
    float* out = (float*)d_out;
    (void)in_sizes; (void)n_in; (void)out_size; (void)d_ws; (void)ws_size;

    dim3 grid(NROWS * 8);   // 1024 rows x 8 chunks
    dim3 block(BD);
    dwt3_fused<<<grid, block, 0, stream>>>(x, h0, h1, out);
}

// Round 2
// 428.988 us; speedup vs baseline: 1.0111x; 1.0111x over previous
//
#include <hip/hip_runtime.h>

// DWT1DForward db4 periodic J=3, fused single kernel, v2.
// x: (16,64,65536) fp32 -> out concat [lo3(1024*8192), hi1(1024*32768),
//                                      hi2(1024*16384), hi3(1024*8192)]
// Identity: out[i] = sum_t h[t] * x[(2i+t-3) mod N]  per level.
//
// v2: chunk 4096 (LDS 29 KB -> 4-5 blocks/CU, 32 waves), pair-processing with
// ds_read_b128/b64 (20 B LDS read per output), ds_write_b64 lo-writes.

#define N0      65536
#define S       4096
#define BD      512

// out element offsets
#define OFF_LO3 0ul
#define OFF_HI1 8388608ul    // 1024*8192
#define OFF_HI2 41943040ul   // + 1024*32768
#define OFF_HI3 58720256ul   // + 1024*16384

// LDS layout
#define SX_OFF  25           // odd & ==1 mod 4: windows even + b128-aligned
#define SX_SZ   4152         // 25 + 4096 + 31
#define SLO1_SZ 2072         // lo1 phys kk in [0,2070), k = base1-9+kk
#define SLO2_SZ 1032         // lo2 phys jj in [0,1032), j = base2-3+jj

// 8-tap quad: from 10-float window v[0..9] compute lo/hi at offsets 0 and 2.
#define QUAD(vv, L0, G0, L1, G1)                                     \
    {                                                                \
        L0 = 0.f; G0 = 0.f; L1 = 0.f; G1 = 0.f;                      \
        _Pragma("unroll")                                            \
        for (int t = 0; t < 8; ++t) {                                \
            L0 = fmaf(h0f[t], vv[t],     L0);                        \
            G0 = fmaf(h1f[t], vv[t],     G0);                        \
            L1 = fmaf(h0f[t], vv[t + 2], L1);                        \
            G1 = fmaf(h1f[t], vv[t + 2], G1);                        \
        }                                                            \
    }

__global__ __launch_bounds__(BD, 4)
void dwt3_fused(const float* __restrict__ x,
                const float* __restrict__ h0,
                const float* __restrict__ h1,
                float* __restrict__ out) {
    __shared__ __align__(16) float sx[SX_SZ];
    __shared__ __align__(16) float slo1[SLO1_SZ];
    __shared__ __align__(16) float slo2[SLO2_SZ];

    const int tid   = threadIdx.x;
    const int bid   = blockIdx.x;
    const int row   = bid >> 4;
    const int chunk = bid & 15;
    const int base  = chunk * S;
    const size_t rowOff = (size_t)row * N0;

    float h0f[8], h1f[8];
#pragma unroll
    for (int t = 0; t < 8; ++t) { h0f[t] = h0[t]; h1f[t] = h1[t]; }

    // ---- stage x chunk + periodic halo ----
    const float4* x4 = reinterpret_cast<const float4*>(x + rowOff + base);
#pragma unroll
    for (int m = tid; m < S / 4; m += BD) {      // exactly 2 iters
        float4 v = x4[m];
        int p = SX_OFF + 4 * m;
        sx[p] = v.x; sx[p+1] = v.y; sx[p+2] = v.z; sx[p+3] = v.w;
    }
    if (tid < 56) {                              // halo: 25 left, 31 right
        int g, p;
        if (tid < 25) { g = base - 25 + tid;       p = tid; }
        else          { g = base + S + (tid - 25); p = SX_OFF + S + (tid - 25); }
        if (g < 0)    g += N0;
        if (g >= N0)  g -= N0;
        sx[p] = x[rowOff + g];
    }
    __syncthreads();

    // ---- level 1: 1035 pairs; kk = 2*pp, k = base1-9+kk ----
    // window for kk: sx phys [4pp+4 .. 4pp+11]; for kk+1: [4pp+6 .. 4pp+13]
    float* hi1 = out + OFF_HI1 + (size_t)row * 32768 + (size_t)chunk * 2048;
    for (int pp = tid; pp < 1035; pp += BD) {    // ~2.02 iters
        const float* sp = sx + 4 * pp + 4;
        float4 a = *reinterpret_cast<const float4*>(sp);
        float4 b = *reinterpret_cast<const float4*>(sp + 4);
        float2 c = *reinterpret_cast<const float2*>(sp + 8);
        float v[10] = {a.x, a.y, a.z, a.w, b.x, b.y, b.z, b.w, c.x, c.y};
        float l0, g0, l1, g1;
        QUAD(v, l0, g0, l1, g1);
        int kk = 2 * pp;
        *reinterpret_cast<float2*>(slo1 + kk) = make_float2(l0, l1);
        unsigned m0 = (unsigned)(kk - 9);
        unsigned m1 = (unsigned)(kk - 8);
        if (m0 < 2048u) hi1[m0] = g0;
        if (m1 < 2048u) hi1[m1] = g1;
    }
    __syncthreads();

    // ---- level 2: 516 pairs; jj = 2*qq, j = base2-3+jj ----
    float* hi2 = out + OFF_HI2 + (size_t)row * 16384 + (size_t)chunk * 1024;
    for (int qq = tid; qq < 516; qq += BD) {     // ~1.01 iters
        const float* sp = slo1 + 4 * qq;
        float4 a = *reinterpret_cast<const float4*>(sp);
        float4 b = *reinterpret_cast<const float4*>(sp + 4);
        float2 c = *reinterpret_cast<const float2*>(sp + 8);
        float v[10] = {a.x, a.y, a.z, a.w, b.x, b.y, b.z, b.w, c.x, c.y};
        float l0, g0, l1, g1;
        QUAD(v, l0, g0, l1, g1);
        int jj = 2 * qq;
        *reinterpret_cast<float2*>(slo2 + jj) = make_float2(l0, l1);
        unsigned m0 = (unsigned)(jj - 3);
        unsigned m1 = (unsigned)(jj - 2);
        if (m0 < 1024u) hi2[m0] = g0;
        if (m1 < 1024u) hi2[m1] = g1;
    }
    __syncthreads();

    // ---- level 3: 256 pairs; i = base3 + 2*pp ----
    float* lo3 = out + OFF_LO3 + (size_t)row * 8192 + (size_t)chunk * 512;
    float* hi3 = out + OFF_HI3 + (size_t)row * 8192 + (size_t)chunk * 512;
    for (int pp = tid; pp < 256; pp += BD) {     // tid<256 only
        const float* sp = slo2 + 4 * pp;
        float4 a = *reinterpret_cast<const float4*>(sp);
        float4 b = *reinterpret_cast<const float4*>(sp + 4);
        float2 c = *reinterpret_cast<const float2*>(sp + 8);
        float v[10] = {a.x, a.y, a.z, a.w, b.x, b.y, b.z, b.w, c.x, c.y};
        float l0, g0, l1, g1;
        QUAD(v, l0, g0, l1, g1);
        *reinterpret_cast<float2*>(lo3 + 2 * pp) = make_float2(l0, l1);
        *reinterpret_cast<float2*>(hi3 + 2 * pp) = make_float2(g0, g1);
    }
}

extern "C" void kernel_launch(void* const* d_in, const int* in_sizes, int n_in,
                              void* d_out, int out_size, void* d_ws, size_t ws_size,
                              hipStream_t stream) {
    const float* x  = (const float*)d_in[0];
    const float* h0 = (const float*)d_in[1];
    const float* h1 = (const float*)d_in[2];
    float* out = (float*)d_out;
    (void)in_sizes; (void)n_in; (void)out_size; (void)d_ws; (void)ws_size;

    dim3 grid(1024 * 16);   // 1024 rows x 16 chunks of 4096
    dim3 block(BD);
    dwt3_fused<<<grid, block, 0, stream>>>(x, h0, h1, out);
}